// Round 1
// baseline (509.067 us; speedup 1.0000x reference)
//
#include <hip/hip_runtime.h>

// Problem constants
#define B_BATCH 8
#define N_SEQ   2048
#define D_DIM   1024
#define DK_DIM  64
#define R_TOT   (B_BATCH * N_SEQ)   // 16384

// ---------------------------------------------------------------------------
// Generic tiled SGEMM: C[M,Nc] = sum_slabs A_s[M,K] * B[Nc,K]^T
//   - 64x64 tile, 256 threads, 4x4 micro-tile, K-chunk 16
//   - grid.x = M/64, grid.y = Nc/64, grid.z = batch * nksplit
//   - A slabs (NSLAB) are summed at staging time (for split-reduction inputs)
//   - nksplit splits the K reduction; partial C goes to ks*splitCStride
// All dims assumed divisible (true for every call here).
// ---------------------------------------------------------------------------
template <int NSLAB>
__global__ __launch_bounds__(256) void gemm_abt(
    const float* __restrict__ A, int lda, long strideA, long slabStride,
    const float* __restrict__ B, int ldb, long strideB,
    float* __restrict__ C, int ldc, long strideC, long splitCStride,
    int K, int nksplit)
{
    const int bm    = blockIdx.x;
    const int bn    = blockIdx.y;
    const int batch = blockIdx.z / nksplit;
    const int ks    = blockIdx.z % nksplit;
    const int Kper  = K / nksplit;

    const float* Ab = A + (long)batch * strideA + (long)bm * 64 * lda + (long)ks * Kper;
    const float* Bb = B + (long)batch * strideB + (long)bn * 64 * ldb + (long)ks * Kper;
    float*       Cb = C + (long)batch * strideC + (long)ks * splitCStride
                        + (long)bm * 64 * ldc + (long)bn * 64;

    __shared__ float As[16][65];
    __shared__ float Bs[16][65];

    const int tid = threadIdx.x;
    const int tx  = tid & 15;        // col quad
    const int ty  = tid >> 4;        // row quad
    const int lr  = tid >> 2;        // staging row 0..63
    const int lk  = (tid & 3) << 2;  // staging k offset 0,4,8,12

    float acc[4][4] = {};

    for (int k0 = 0; k0 < Kper; k0 += 16) {
        float4 av = *(const float4*)(Ab + (long)lr * lda + k0 + lk);
        float4 bv = *(const float4*)(Bb + (long)lr * ldb + k0 + lk);
#pragma unroll
        for (int s = 1; s < NSLAB; ++s) {
            float4 a2 = *(const float4*)(Ab + (long)s * slabStride + (long)lr * lda + k0 + lk);
            av.x += a2.x; av.y += a2.y; av.z += a2.z; av.w += a2.w;
        }
        __syncthreads();
        As[lk + 0][lr] = av.x; As[lk + 1][lr] = av.y;
        As[lk + 2][lr] = av.z; As[lk + 3][lr] = av.w;
        Bs[lk + 0][lr] = bv.x; Bs[lk + 1][lr] = bv.y;
        Bs[lk + 2][lr] = bv.z; Bs[lk + 3][lr] = bv.w;
        __syncthreads();
#pragma unroll
        for (int kk = 0; kk < 16; ++kk) {
            float a[4], b[4];
#pragma unroll
            for (int i = 0; i < 4; ++i) a[i] = As[kk][ty * 4 + i];
#pragma unroll
            for (int j = 0; j < 4; ++j) b[j] = Bs[kk][tx * 4 + j];
#pragma unroll
            for (int i = 0; i < 4; ++i)
#pragma unroll
                for (int j = 0; j < 4; ++j)
                    acc[i][j] = fmaf(a[i], b[j], acc[i][j]);
        }
    }

#pragma unroll
    for (int i = 0; i < 4; ++i) {
        float4 v = make_float4(acc[i][0], acc[i][1], acc[i][2], acc[i][3]);
        *(float4*)(Cb + (long)(ty * 4 + i) * ldc + tx * 4) = v;
    }
}

// ---------------------------------------------------------------------------
// Spart[s][b][j,d] = sum_{n in slice s} K[b,n,j] * x[b,n,d]
// grid: (d-tile 16, n-split 4, batch 8); 64(j) x 64(d) tile per block.
// ---------------------------------------------------------------------------
__global__ __launch_bounds__(256) void s_split_kernel(
    const float* __restrict__ Kb, const float* __restrict__ x,
    float* __restrict__ Spart)
{
    const int d0 = blockIdx.x * 64;
    const int s  = blockIdx.y;
    const int b  = blockIdx.z;
    const int n0 = s * (N_SEQ / 4);  // 512-row slice

    const float* Kp = Kb + ((long)b * N_SEQ + n0) * DK_DIM;
    const float* xp = x  + ((long)b * N_SEQ + n0) * D_DIM + d0;
    float*       Cp = Spart + ((long)(s * B_BATCH + b)) * DK_DIM * D_DIM + d0;

    __shared__ float Ks[16][65];
    __shared__ float xs[16][65];

    const int tid = threadIdx.x;
    const int tx  = tid & 15;        // d quad
    const int ty  = tid >> 4;        // j quad
    const int lr  = tid >> 4;        // staging row 0..15
    const int lc  = (tid & 15) * 4;  // staging col 0..60

    float acc[4][4] = {};

    for (int c = 0; c < 32; ++c) {   // 32 chunks x 16 n = 512
        const int nb = c * 16;
        float4 kv = *(const float4*)(Kp + (long)(nb + lr) * DK_DIM + lc);
        float4 xv = *(const float4*)(xp + (long)(nb + lr) * D_DIM + lc);
        __syncthreads();
        Ks[lr][lc + 0] = kv.x; Ks[lr][lc + 1] = kv.y;
        Ks[lr][lc + 2] = kv.z; Ks[lr][lc + 3] = kv.w;
        xs[lr][lc + 0] = xv.x; xs[lr][lc + 1] = xv.y;
        xs[lr][lc + 2] = xv.z; xs[lr][lc + 3] = xv.w;
        __syncthreads();
#pragma unroll
        for (int nn = 0; nn < 16; ++nn) {
            float a[4], b[4];
#pragma unroll
            for (int i = 0; i < 4; ++i) a[i] = Ks[nn][ty * 4 + i];
#pragma unroll
            for (int j = 0; j < 4; ++j) b[j] = xs[nn][tx * 4 + j];
#pragma unroll
            for (int i = 0; i < 4; ++i)
#pragma unroll
                for (int j = 0; j < 4; ++j)
                    acc[i][j] = fmaf(a[i], b[j], acc[i][j]);
        }
    }

#pragma unroll
    for (int i = 0; i < 4; ++i) {
        float4 v = make_float4(acc[i][0], acc[i][1], acc[i][2], acc[i][3]);
        *(float4*)(Cp + (long)(ty * 4 + i) * D_DIM + tx * 4) = v;
    }
}

// ---------------------------------------------------------------------------
// fc[n,k] += sum_j Q[n,j] * PB[b][j,k]   (PB = sum of 16 K-split slabs)
// grid.x = R/64; block handles 64 rows x 64 k.
// ---------------------------------------------------------------------------
__global__ __launch_bounds__(256) void fc2_add_kernel(
    const float* __restrict__ Q, const float* __restrict__ PBpart,
    float* __restrict__ fc)
{
    const int row0 = blockIdx.x * 64;
    const int b    = row0 >> 11;  // / 2048

    __shared__ float PBs[64][65];
    __shared__ float Qs[64][65];

    const int tid = threadIdx.x;
    const float* pb = PBpart + (long)b * 4096;

    for (int i = tid; i < 4096; i += 256) {
        float v = 0.f;
#pragma unroll
        for (int s2 = 0; s2 < 16; ++s2) v += pb[(long)s2 * 32768 + i];
        PBs[i >> 6][i & 63] = v;
    }
    for (int i = tid; i < 4096; i += 256) {
        Qs[i >> 6][i & 63] = Q[(long)(row0 + (i >> 6)) * DK_DIM + (i & 63)];
    }
    __syncthreads();

    const int tx = tid & 15;   // k quad
    const int ty = tid >> 4;   // row quad
    float acc[4][4] = {};
    for (int j = 0; j < 64; ++j) {
        float a[4], b2[4];
#pragma unroll
        for (int i = 0; i < 4; ++i) a[i] = Qs[ty * 4 + i][j];
#pragma unroll
        for (int jj = 0; jj < 4; ++jj) b2[jj] = PBs[j][tx * 4 + jj];
#pragma unroll
        for (int i = 0; i < 4; ++i)
#pragma unroll
            for (int jj = 0; jj < 4; ++jj)
                acc[i][jj] = fmaf(a[i], b2[jj], acc[i][jj]);
    }

#pragma unroll
    for (int i = 0; i < 4; ++i) {
        float* p = fc + (long)(row0 + ty * 4 + i) * DK_DIM + tx * 4;
        p[0] += acc[i][0]; p[1] += acc[i][1];
        p[2] += acc[i][2]; p[3] += acc[i][3];
    }
}

// ---------------------------------------------------------------------------
extern "C" void kernel_launch(void* const* d_in, const int* in_sizes, int n_in,
                              void* d_out, int out_size, void* d_ws, size_t ws_size,
                              hipStream_t stream)
{
    const float* x  = (const float*)d_in[0];
    const float* Wq = (const float*)d_in[1];
    const float* Wk = (const float*)d_in[2];
    const float* Wv = (const float*)d_in[3];
    const float* W1 = (const float*)d_in[4];
    const float* W2 = (const float*)d_in[5];
    float* out = (float*)d_out;

    // Workspace layout (floats):
    //   Qb     : R*64            = 1,048,576
    //   Kb     : R*64            = 1,048,576
    //   Spart  : 4*8*64*1024     = 2,097,152
    //   Mpart  : 2*8*64*1024     = 1,048,576
    //   PBpart : 16*8*64*64      =   524,288
    //   fcb    : R*64            = 1,048,576
    const size_t nQ = (size_t)R_TOT * DK_DIM;      // 1048576
    const size_t nS = 4ul * B_BATCH * DK_DIM * D_DIM;  // 2097152
    const size_t nM = 2ul * B_BATCH * DK_DIM * D_DIM;  // 1048576
    const size_t nPB = 16ul * B_BATCH * DK_DIM * DK_DIM; // 524288
    const size_t needF = nQ * 2 + nS + nM + nPB + nQ;    // 6,815,744 floats

    float *Qb, *Kb, *Sp, *Mp, *PBp, *fcb;
    if (ws_size >= needF * sizeof(float)) {
        float* w = (float*)d_ws;
        Qb = w;  Kb = Qb + nQ;  Sp = Kb + nQ;  Mp = Sp + nS;
        PBp = Mp + nM;  fcb = PBp + nPB;
    } else {
        // Fallback: big scratch lives in d_out (fully overwritten by the final
        // GEMM after all consumers finished); fc (read by the final GEMM) in ws.
        float* ob = (float*)d_out;
        Qb = ob;  Kb = Qb + nQ;  Sp = Kb + nQ;  Mp = Sp + nS;  PBp = Mp + nM;
        fcb = (float*)d_ws;
    }

    // 1) Q = x * Wq^T        [16384,64]
    gemm_abt<1><<<dim3(256, 1, 1), 256, 0, stream>>>(
        x, D_DIM, 0, 0, Wq, D_DIM, 0, Qb, DK_DIM, 0, 0, D_DIM, 1);
    // 2) K = x * Wk^T        [16384,64]
    gemm_abt<1><<<dim3(256, 1, 1), 256, 0, stream>>>(
        x, D_DIM, 0, 0, Wk, D_DIM, 0, Kb, DK_DIM, 0, 0, D_DIM, 1);
    // 3) Spart[s][b] = K_slice^T * x_slice     (4-way n-split)
    s_split_kernel<<<dim3(16, 4, 8), 256, 0, stream>>>(Kb, x, Sp);
    // 4) Mpart[ks][b] = (sum_s Spart[s][b]) * Wv^T, K-split 2
    gemm_abt<4><<<dim3(1, 16, 16), 256, 0, stream>>>(
        Sp, D_DIM, (long)DK_DIM * D_DIM, (long)B_BATCH * DK_DIM * D_DIM,
        Wv, D_DIM, 0,
        Mp, D_DIM, (long)DK_DIM * D_DIM, (long)B_BATCH * DK_DIM * D_DIM,
        D_DIM, 2);
    // 5) PBpart[ks][b] = (sum_s Mpart[s][b]) * W1^T, K-split 16
    gemm_abt<2><<<dim3(1, 1, 128), 256, 0, stream>>>(
        Mp, D_DIM, (long)DK_DIM * D_DIM, (long)B_BATCH * DK_DIM * D_DIM,
        W1, D_DIM, 0,
        PBp, DK_DIM, (long)DK_DIM * DK_DIM, (long)B_BATCH * DK_DIM * DK_DIM,
        D_DIM, 16);
    // 6) fc = x * W1^T       [16384,64]
    gemm_abt<1><<<dim3(256, 1, 1), 256, 0, stream>>>(
        x, D_DIM, 0, 0, W1, D_DIM, 0, fcb, DK_DIM, 0, 0, D_DIM, 1);
    // 7) fc += Q * PB[b]
    fc2_add_kernel<<<dim3(256, 1, 1), 256, 0, stream>>>(Qb, PBp, fcb);
    // 8) out = fc * W2^T     [16384,1024]
    gemm_abt<1><<<dim3(256, 16, 1), 256, 0, stream>>>(
        fcb, DK_DIM, 0, 0, W2, DK_DIM, 0, out, D_DIM, 0, 0, DK_DIM, 1);
}

// Round 2
// 398.462 us; speedup vs baseline: 1.2776x; 1.2776x over previous
//
#include <hip/hip_runtime.h>

typedef __attribute__((ext_vector_type(8))) __bf16 bf16x8;
typedef __attribute__((ext_vector_type(4))) float f32x4;
typedef unsigned short u16;

#define MFMA16(a, b, c) __builtin_amdgcn_mfma_f32_16x16x32_bf16(a, b, c, 0, 0, 0)

__device__ __forceinline__ u16 f2bf(float f) {
    unsigned u = __float_as_uint(f);
    unsigned r = ((u >> 16) & 1u) + 0x7fffu;  // RNE
    return (u16)((u + r) >> 16);
}
__device__ __forceinline__ float bf2f(u16 h) {
    return __uint_as_float(((unsigned)h) << 16);
}
// LDS fragment load: row = rtile + (lane&15), k = kofs + (lane>>4)*8, row stride 72 u16 (144B, 16B-aligned)
__device__ __forceinline__ bf16x8 frag(const u16* base, int rtile, int lane, int kofs) {
    return *(const bf16x8*)(base + (rtile + (lane & 15)) * 72 + kofs + (lane >> 4) * 8);
}

// ---------------------------------------------------------------------------
// Fused: Q = x*Wq^T (bf16), K = x*Wk^T (bf16), fc = x*W1^T (fp32, 3-product
// bf16-split for full precision). One block = 64 rows of x, K-loop over 1024.
// ---------------------------------------------------------------------------
__global__ __launch_bounds__(256) void qkf_kernel(
    const float* __restrict__ x, const float* __restrict__ Wq,
    const float* __restrict__ Wk, const float* __restrict__ W1,
    u16* __restrict__ Qb, u16* __restrict__ Kb, float* __restrict__ fcb)
{
    __shared__ __align__(16) u16 SM[6 * 4608];
    u16* Xh  = SM;
    u16* Xl  = SM + 4608;
    u16* Wqh = SM + 2 * 4608;
    u16* Wkh = SM + 3 * 4608;
    u16* W1h = SM + 4 * 4608;
    u16* W1l = SM + 5 * 4608;

    const int tid  = threadIdx.x;
    const int lane = tid & 63;
    const int wv   = tid >> 6;
    const int r0   = wv * 16;
    const long row0 = (long)blockIdx.x * 64;

    const f32x4 zero = {0.f, 0.f, 0.f, 0.f};
    f32x4 qa[4], ka[4], fa[4];
    for (int i = 0; i < 4; ++i) { qa[i] = zero; ka[i] = zero; fa[i] = zero; }

    const int sr = tid >> 4;         // staging row 0..15
    const int sk = (tid & 15) * 4;   // staging k   0..60

    for (int ch = 0; ch < 16; ++ch) {
        const int k0 = ch * 64;
        for (int i = 0; i < 4; ++i) {
            int r = sr + i * 16;
            float4 v = *(const float4*)(x + (row0 + r) * 1024 + k0 + sk);
            ushort4 h, l;
            h.x = f2bf(v.x); l.x = f2bf(v.x - bf2f(h.x));
            h.y = f2bf(v.y); l.y = f2bf(v.y - bf2f(h.y));
            h.z = f2bf(v.z); l.z = f2bf(v.z - bf2f(h.z));
            h.w = f2bf(v.w); l.w = f2bf(v.w - bf2f(h.w));
            *(ushort4*)&Xh[r * 72 + sk] = h;
            *(ushort4*)&Xl[r * 72 + sk] = l;
        }
        for (int i = 0; i < 4; ++i) {
            int r = sr + i * 16;
            float4 vq = *(const float4*)(Wq + (long)r * 1024 + k0 + sk);
            ushort4 hq;
            hq.x = f2bf(vq.x); hq.y = f2bf(vq.y); hq.z = f2bf(vq.z); hq.w = f2bf(vq.w);
            *(ushort4*)&Wqh[r * 72 + sk] = hq;
            float4 vk = *(const float4*)(Wk + (long)r * 1024 + k0 + sk);
            ushort4 hk;
            hk.x = f2bf(vk.x); hk.y = f2bf(vk.y); hk.z = f2bf(vk.z); hk.w = f2bf(vk.w);
            *(ushort4*)&Wkh[r * 72 + sk] = hk;
            float4 vw = *(const float4*)(W1 + (long)r * 1024 + k0 + sk);
            ushort4 hw, lw;
            hw.x = f2bf(vw.x); lw.x = f2bf(vw.x - bf2f(hw.x));
            hw.y = f2bf(vw.y); lw.y = f2bf(vw.y - bf2f(hw.y));
            hw.z = f2bf(vw.z); lw.z = f2bf(vw.z - bf2f(hw.z));
            hw.w = f2bf(vw.w); lw.w = f2bf(vw.w - bf2f(hw.w));
            *(ushort4*)&W1h[r * 72 + sk] = hw;
            *(ushort4*)&W1l[r * 72 + sk] = lw;
        }
        __syncthreads();
#pragma unroll
        for (int kk = 0; kk < 64; kk += 32) {
            bf16x8 ah = frag(Xh, r0, lane, kk);
            bf16x8 al = frag(Xl, r0, lane, kk);
#pragma unroll
            for (int ct = 0; ct < 4; ++ct) {
                bf16x8 bq = frag(Wqh, ct * 16, lane, kk);
                qa[ct] = MFMA16(ah, bq, qa[ct]);
                bf16x8 bk = frag(Wkh, ct * 16, lane, kk);
                ka[ct] = MFMA16(ah, bk, ka[ct]);
                bf16x8 bh = frag(W1h, ct * 16, lane, kk);
                bf16x8 bl = frag(W1l, ct * 16, lane, kk);
                fa[ct] = MFMA16(ah, bh, fa[ct]);
                fa[ct] = MFMA16(al, bh, fa[ct]);
                fa[ct] = MFMA16(ah, bl, fa[ct]);
            }
        }
        __syncthreads();
    }

    // fc: fp32 scalar stores straight from acc (C layout: col=lane&15, row=quad*4+g)
    {
        int rr = r0 + (lane >> 4) * 4;
        int cc = lane & 15;
        for (int ct = 0; ct < 4; ++ct)
            for (int g = 0; g < 4; ++g)
                fcb[(row0 + rr + g) * 64 + ct * 16 + cc] = fa[ct][g];
    }
    // Q then K: repack through LDS (stride 65 fp32, conflict-free) -> 32B bf16 stores
    float* rep = (float*)SM;
    for (int pass = 0; pass < 2; ++pass) {
        const f32x4* src = (pass == 0) ? qa : ka;
        u16* dst = (pass == 0) ? Qb : Kb;
        __syncthreads();
        int rr = r0 + (lane >> 4) * 4;
        int cc = lane & 15;
        for (int ct = 0; ct < 4; ++ct)
            for (int g = 0; g < 4; ++g)
                rep[(rr + g) * 65 + ct * 16 + cc] = src[ct][g];
        __syncthreads();
        int r = tid >> 2, c0 = (tid & 3) * 16;
        __align__(16) u16 tmp[16];
        for (int i = 0; i < 16; ++i) tmp[i] = f2bf(rep[r * 65 + c0 + i]);
        *(uint4*)(dst + (row0 + r) * 64 + c0) = *(uint4*)&tmp[0];
        *(uint4*)(dst + (row0 + r) * 64 + c0 + 8) = *(uint4*)&tmp[8];
    }
}

// ---------------------------------------------------------------------------
// Generic 64x64-tile MFMA NT-GEMM: C[m,n] (+)= sum_k A[m,k]*B[n,k]
// AMODE/BMODE: 0 = fp32 rows=[dim][k] (optional slab-sum, optional hi/lo split)
//              1 = bf16 rows=[dim][k]
//              2 = fp32 transposed source [k][dim]
//              3 = bf16 transposed source [k][dim]
// SPLIT: stage hi+lo of both operands, 3-product MFMA (fp32-class accuracy).
// grid = (Mtiles, Ntiles, batch*nksplit). K-split partials via splitC.
// ---------------------------------------------------------------------------
template <int AMODE, int BMODE, bool SPLIT, int ASLAB, int BSLAB, bool ACCUM>
__global__ __launch_bounds__(256) void mm_nt(
    const void* __restrict__ Ap, int lda, long bsA, long slabA,
    const void* __restrict__ Bp, int ldb, long bsB, long slabB,
    float* __restrict__ Cp, int ldc, long bsC, long splitC,
    int Kred, int nksplit)
{
    __shared__ __align__(16) u16 Ah[4608];
    __shared__ __align__(16) u16 Al[4608];
    __shared__ __align__(16) u16 Bh[4608];
    __shared__ __align__(16) u16 Bl[4608];

    const int tid = threadIdx.x, lane = tid & 63, wv = tid >> 6;
    const int bm = blockIdx.x, bn = blockIdx.y;
    const int batch = blockIdx.z / nksplit;
    const int ks = blockIdx.z % nksplit;
    const int Kper = Kred / nksplit;
    const long kOff = (long)ks * Kper;

    const f32x4 zero = {0.f, 0.f, 0.f, 0.f};
    f32x4 acc[4];
    for (int i = 0; i < 4; ++i) acc[i] = zero;

    for (int k0 = 0; k0 < Kper; k0 += 64) {
        // ---------------- stage A ----------------
        if constexpr (AMODE == 0) {
            const float* A = (const float*)Ap + (long)batch * bsA + (long)bm * 64 * lda + kOff + k0;
            for (int i = 0; i < 4; ++i) {
                int r = (tid >> 4) + i * 16, k = (tid & 15) * 4;
                const float* p = A + (long)r * lda + k;
                float4 v = *(const float4*)p;
#pragma unroll
                for (int s = 1; s < ASLAB; ++s) {
                    float4 w = *(const float4*)(p + (long)s * slabA);
                    v.x += w.x; v.y += w.y; v.z += w.z; v.w += w.w;
                }
                ushort4 h;
                h.x = f2bf(v.x); h.y = f2bf(v.y); h.z = f2bf(v.z); h.w = f2bf(v.w);
                *(ushort4*)&Ah[r * 72 + k] = h;
                if constexpr (SPLIT) {
                    ushort4 l;
                    l.x = f2bf(v.x - bf2f(h.x)); l.y = f2bf(v.y - bf2f(h.y));
                    l.z = f2bf(v.z - bf2f(h.z)); l.w = f2bf(v.w - bf2f(h.w));
                    *(ushort4*)&Al[r * 72 + k] = l;
                }
            }
        } else if constexpr (AMODE == 1) {
            const u16* A = (const u16*)Ap + (long)batch * bsA + (long)bm * 64 * lda + kOff + k0;
            for (int i = 0; i < 2; ++i) {
                int r = (tid >> 3) + i * 32, k = (tid & 7) * 8;
                uint4 v = *(const uint4*)(A + (long)r * lda + k);
                *(uint4*)&Ah[r * 72 + k] = v;
            }
        } else if constexpr (AMODE == 2) {
            const float* A = (const float*)Ap + (long)batch * bsA + (kOff + k0) * lda + bm * 64;
            for (int i = 0; i < 16; ++i) {
                int kk = (tid >> 6) + i * 4, c = tid & 63;
                Ah[c * 72 + kk] = f2bf(A[(long)kk * lda + c]);
            }
        } else {
            const u16* A = (const u16*)Ap + (long)batch * bsA + (kOff + k0) * lda + bm * 64;
            for (int i = 0; i < 16; ++i) {
                int kk = (tid >> 6) + i * 4, c = tid & 63;
                Ah[c * 72 + kk] = A[(long)kk * lda + c];
            }
        }
        // ---------------- stage B ----------------
        if constexpr (BMODE == 0) {
            const float* B = (const float*)Bp + (long)batch * bsB + (long)bn * 64 * ldb + kOff + k0;
            for (int i = 0; i < 4; ++i) {
                int r = (tid >> 4) + i * 16, k = (tid & 15) * 4;
                const float* p = B + (long)r * ldb + k;
                float4 v = *(const float4*)p;
#pragma unroll
                for (int s = 1; s < BSLAB; ++s) {
                    float4 w = *(const float4*)(p + (long)s * slabB);
                    v.x += w.x; v.y += w.y; v.z += w.z; v.w += w.w;
                }
                ushort4 h;
                h.x = f2bf(v.x); h.y = f2bf(v.y); h.z = f2bf(v.z); h.w = f2bf(v.w);
                *(ushort4*)&Bh[r * 72 + k] = h;
                if constexpr (SPLIT) {
                    ushort4 l;
                    l.x = f2bf(v.x - bf2f(h.x)); l.y = f2bf(v.y - bf2f(h.y));
                    l.z = f2bf(v.z - bf2f(h.z)); l.w = f2bf(v.w - bf2f(h.w));
                    *(ushort4*)&Bl[r * 72 + k] = l;
                }
            }
        } else if constexpr (BMODE == 1) {
            const u16* B = (const u16*)Bp + (long)batch * bsB + (long)bn * 64 * ldb + kOff + k0;
            for (int i = 0; i < 2; ++i) {
                int r = (tid >> 3) + i * 32, k = (tid & 7) * 8;
                uint4 v = *(const uint4*)(B + (long)r * ldb + k);
                *(uint4*)&Bh[r * 72 + k] = v;
            }
        } else if constexpr (BMODE == 2) {
            const float* B = (const float*)Bp + (long)batch * bsB + (kOff + k0) * ldb + bn * 64;
            for (int i = 0; i < 16; ++i) {
                int kk = (tid >> 6) + i * 4, c = tid & 63;
                Bh[c * 72 + kk] = f2bf(B[(long)kk * ldb + c]);
            }
        } else {
            const u16* B = (const u16*)Bp + (long)batch * bsB + (kOff + k0) * ldb + bn * 64;
            for (int i = 0; i < 16; ++i) {
                int kk = (tid >> 6) + i * 4, c = tid & 63;
                Bh[c * 72 + kk] = B[(long)kk * ldb + c];
            }
        }
        __syncthreads();
#pragma unroll
        for (int kk2 = 0; kk2 < 64; kk2 += 32) {
            bf16x8 ah = frag(Ah, wv * 16, lane, kk2);
            bf16x8 al;
            if constexpr (SPLIT) al = frag(Al, wv * 16, lane, kk2);
#pragma unroll
            for (int ct = 0; ct < 4; ++ct) {
                bf16x8 bh = frag(Bh, ct * 16, lane, kk2);
                acc[ct] = MFMA16(ah, bh, acc[ct]);
                if constexpr (SPLIT) {
                    bf16x8 bl = frag(Bl, ct * 16, lane, kk2);
                    acc[ct] = MFMA16(al, bh, acc[ct]);
                    acc[ct] = MFMA16(ah, bl, acc[ct]);
                }
            }
        }
        __syncthreads();
    }

    float* C = Cp + (long)batch * bsC + (long)ks * splitC + (long)bm * 64 * ldc + (long)bn * 64;
    const int rr = wv * 16 + (lane >> 4) * 4;
    const int cc = lane & 15;
#pragma unroll
    for (int ct = 0; ct < 4; ++ct)
#pragma unroll
        for (int g = 0; g < 4; ++g) {
            long idx = (long)(rr + g) * ldc + ct * 16 + cc;
            if constexpr (ACCUM) C[idx] += acc[ct][g];
            else                 C[idx] = acc[ct][g];
        }
}

// ---------------------------------------------------------------------------
extern "C" void kernel_launch(void* const* d_in, const int* in_sizes, int n_in,
                              void* d_out, int out_size, void* d_ws, size_t ws_size,
                              hipStream_t stream)
{
    const float* x  = (const float*)d_in[0];
    const float* Wq = (const float*)d_in[1];
    const float* Wk = (const float*)d_in[2];
    const float* Wv = (const float*)d_in[3];
    const float* W1 = (const float*)d_in[4];
    const float* W2 = (const float*)d_in[5];
    float* out = (float*)d_out;

    // Scratch (bytes): Q bf16 2M, K bf16 2M, fc f32 4M, Spart f32 4M, M f32 2M, PBT f32 .5M
    const size_t QB = 2097152, KBY = 2097152, FCB = 4194304,
                 SPB = 4194304, MBY = 2097152, PBB = 524288;
    const size_t need = QB + KBY + FCB + SPB + MBY + PBB;  // 15,204,352

    u16 *Qb, *Kb;
    float *fcb, *Sp, *Mp, *PBp;
    if (ws_size >= need) {
        char* w = (char*)d_ws;
        Qb  = (u16*)w;                 w += QB;
        Kb  = (u16*)w;                 w += KBY;
        fcb = (float*)w;               w += FCB;
        Sp  = (float*)w;               w += SPB;
        Mp  = (float*)w;               w += MBY;
        PBp = (float*)w;
    } else {
        // Big scratch in d_out (all dead before the final GEMM overwrites it);
        // fc (read by final GEMM while it writes d_out) in ws.
        char* o = (char*)d_out;
        Qb  = (u16*)o;                 o += QB;
        Kb  = (u16*)o;                 o += KBY;
        Sp  = (float*)o;               o += SPB;
        Mp  = (float*)o;               o += MBY;
        PBp = (float*)o;
        fcb = (float*)d_ws;
    }

    // 1) Q,K (bf16) + fc = x*W1^T (fp32, split-accurate); 256 blocks x 64 rows
    qkf_kernel<<<dim3(256), 256, 0, stream>>>(x, Wq, Wk, W1, Qb, Kb, fcb);

    // 2) Spart[ks][b][j][d] = sum_n K[b,n,j] * x[b,n,d]; A=K bf16-trans, B=x f32-trans
    mm_nt<3, 2, false, 1, 1, false><<<dim3(1, 16, 16), 256, 0, stream>>>(
        Kb, 64, 131072L, 0,   x, 1024, 2097152L, 0,
        Sp, 1024, 65536L, 524288L, 2048, 2);

    // 3) M[b][j][e] = sum_d (Spart0+Spart1)[j,d] * Wv[e,d]
    mm_nt<0, 0, false, 2, 1, false><<<dim3(1, 16, 8), 256, 0, stream>>>(
        Sp, 1024, 65536L, 524288L,   Wv, 1024, 0, 0,
        Mp, 1024, 65536L, 0, 1024, 1);

    // 4) PBTpart[ks][b][k][j] = sum_e W1[k,e] * M[b,j,e]  (K-split 4)
    mm_nt<0, 0, false, 1, 1, false><<<dim3(1, 1, 32), 256, 0, stream>>>(
        W1, 1024, 0, 0,   Mp, 1024, 65536L, 0,
        PBp, 64, 4096L, 32768L, 1024, 4);

    // 5) fc[b,n,k] += sum_j Q[b,n,j] * PBT[b][k,j]  (B slab-sums 4 partials)
    mm_nt<1, 0, false, 1, 4, true><<<dim3(32, 1, 8), 256, 0, stream>>>(
        Qb, 64, 131072L, 0,   PBp, 64, 4096L, 32768L,
        fcb, 64, 131072L, 0, 64, 1);

    // 6) out = fc * W2^T (split-accurate both operands)
    mm_nt<0, 0, true, 1, 1, false><<<dim3(256, 16, 1), 256, 0, stream>>>(
        fcb, 64, 0, 0,   W2, 64, 0, 0,
        out, 1024, 0, 0, 64, 1);
}

// Round 3
// 220.382 us; speedup vs baseline: 2.3099x; 1.8081x over previous
//
#include <hip/hip_runtime.h>

typedef __attribute__((ext_vector_type(8))) __bf16 bf16x8;
typedef __attribute__((ext_vector_type(4))) float f32x4;
typedef unsigned short u16;

#define MFMA16(a, b, c) __builtin_amdgcn_mfma_f32_16x16x32_bf16(a, b, c, 0, 0, 0)

__device__ __forceinline__ u16 f2bf(float f) {
    unsigned u = __float_as_uint(f);
    unsigned r = ((u >> 16) & 1u) + 0x7fffu;  // RNE
    return (u16)((u + r) >> 16);
}
__device__ __forceinline__ float bf2f(u16 h) {
    return __uint_as_float(((unsigned)h) << 16);
}
// LDS fragment: row = rtile + (lane&15), k = kofs + (lane>>4)*8; row stride 72 u16 (144B)
__device__ __forceinline__ bf16x8 frag(const u16* base, int rtile, int lane, int kofs) {
    return *(const bf16x8*)(base + (rtile + (lane & 15)) * 72 + kofs + (lane >> 4) * 8);
}

// ---------------------------------------------------------------------------
// Fused: Q = x*Wq^T (bf16), K = x*Wk^T (bf16), fc = x*W1^T (fp32 via 3-product
// bf16 split). 64 rows per block; two-phase staging + next-chunk reg prefetch.
// ---------------------------------------------------------------------------
__global__ __launch_bounds__(256) void qkf_kernel(
    const float* __restrict__ x, const float* __restrict__ Wq,
    const float* __restrict__ Wk, const float* __restrict__ W1,
    u16* __restrict__ Qb, u16* __restrict__ Kb, float* __restrict__ fcb)
{
    __shared__ __align__(16) u16 SM[6 * 4608];
    u16* Xh  = SM;
    u16* Xl  = SM + 4608;
    u16* Wqh = SM + 2 * 4608;
    u16* Wkh = SM + 3 * 4608;
    u16* W1h = SM + 4 * 4608;
    u16* W1l = SM + 5 * 4608;

    const int tid  = threadIdx.x;
    const int lane = tid & 63;
    const int wv   = tid >> 6;
    const int r0   = wv * 16;
    const long row0 = (long)blockIdx.x * 64;

    const f32x4 zero = {0.f, 0.f, 0.f, 0.f};
    f32x4 qa[4], ka[4], fa[4];
#pragma unroll
    for (int i = 0; i < 4; ++i) { qa[i] = zero; ka[i] = zero; fa[i] = zero; }

    const int sr = tid >> 4;         // staging row 0..15
    const int sk = (tid & 15) * 4;   // staging k   0..60

    float4 xv[4], qv[4], kv[4], w1v[4];
#define QKF_LOAD(K0)                                                          \
    {                                                                         \
        _Pragma("unroll")                                                     \
        for (int i = 0; i < 4; ++i) {                                         \
            int r = sr + i * 16;                                              \
            xv[i]  = *(const float4*)(x  + (row0 + r) * 1024 + (K0) + sk);    \
            qv[i]  = *(const float4*)(Wq + (long)r * 1024 + (K0) + sk);       \
            kv[i]  = *(const float4*)(Wk + (long)r * 1024 + (K0) + sk);       \
            w1v[i] = *(const float4*)(W1 + (long)r * 1024 + (K0) + sk);       \
        }                                                                     \
    }

    QKF_LOAD(0)
    for (int ch = 0; ch < 16; ++ch) {
        if (ch) __syncthreads();
#pragma unroll
        for (int i = 0; i < 4; ++i) {
            int r = sr + i * 16;
            ushort4 h, l;
            h.x = f2bf(xv[i].x); l.x = f2bf(xv[i].x - bf2f(h.x));
            h.y = f2bf(xv[i].y); l.y = f2bf(xv[i].y - bf2f(h.y));
            h.z = f2bf(xv[i].z); l.z = f2bf(xv[i].z - bf2f(h.z));
            h.w = f2bf(xv[i].w); l.w = f2bf(xv[i].w - bf2f(h.w));
            *(ushort4*)&Xh[r * 72 + sk] = h;
            *(ushort4*)&Xl[r * 72 + sk] = l;
            ushort4 hq;
            hq.x = f2bf(qv[i].x); hq.y = f2bf(qv[i].y);
            hq.z = f2bf(qv[i].z); hq.w = f2bf(qv[i].w);
            *(ushort4*)&Wqh[r * 72 + sk] = hq;
            ushort4 hk;
            hk.x = f2bf(kv[i].x); hk.y = f2bf(kv[i].y);
            hk.z = f2bf(kv[i].z); hk.w = f2bf(kv[i].w);
            *(ushort4*)&Wkh[r * 72 + sk] = hk;
            ushort4 hw, lw;
            hw.x = f2bf(w1v[i].x); lw.x = f2bf(w1v[i].x - bf2f(hw.x));
            hw.y = f2bf(w1v[i].y); lw.y = f2bf(w1v[i].y - bf2f(hw.y));
            hw.z = f2bf(w1v[i].z); lw.z = f2bf(w1v[i].z - bf2f(hw.z));
            hw.w = f2bf(w1v[i].w); lw.w = f2bf(w1v[i].w - bf2f(hw.w));
            *(ushort4*)&W1h[r * 72 + sk] = hw;
            *(ushort4*)&W1l[r * 72 + sk] = lw;
        }
        __syncthreads();
        if (ch < 15) QKF_LOAD((ch + 1) * 64)
#pragma unroll
        for (int kk = 0; kk < 64; kk += 32) {
            bf16x8 ah = frag(Xh, r0, lane, kk);
            bf16x8 al = frag(Xl, r0, lane, kk);
#pragma unroll
            for (int ct = 0; ct < 4; ++ct) {
                qa[ct] = MFMA16(ah, frag(Wqh, ct * 16, lane, kk), qa[ct]);
                ka[ct] = MFMA16(ah, frag(Wkh, ct * 16, lane, kk), ka[ct]);
                bf16x8 bh = frag(W1h, ct * 16, lane, kk);
                fa[ct] = MFMA16(ah, bh, fa[ct]);
                fa[ct] = MFMA16(al, bh, fa[ct]);
                fa[ct] = MFMA16(ah, frag(W1l, ct * 16, lane, kk), fa[ct]);
            }
        }
    }
#undef QKF_LOAD

    // fc: fp32 stores from acc (C layout: col=lane&15, row=quad*4+g)
    {
        int rr = r0 + (lane >> 4) * 4;
        int cc = lane & 15;
#pragma unroll
        for (int ct = 0; ct < 4; ++ct)
#pragma unroll
            for (int g = 0; g < 4; ++g)
                fcb[(row0 + rr + g) * 64 + ct * 16 + cc] = fa[ct][g];
    }
    // Q then K: repack through LDS -> 16B bf16 stores
    float* rep = (float*)SM;
    for (int pass = 0; pass < 2; ++pass) {
        const f32x4* src = (pass == 0) ? qa : ka;
        u16* dst = (pass == 0) ? Qb : Kb;
        __syncthreads();
        int rr = r0 + (lane >> 4) * 4;
        int cc = lane & 15;
#pragma unroll
        for (int ct = 0; ct < 4; ++ct)
#pragma unroll
            for (int g = 0; g < 4; ++g)
                rep[(rr + g) * 65 + ct * 16 + cc] = src[ct][g];
        __syncthreads();
        int r = tid >> 2, c0 = (tid & 3) * 16;
        __align__(16) u16 tmp[16];
#pragma unroll
        for (int i = 0; i < 16; ++i) tmp[i] = f2bf(rep[r * 65 + c0 + i]);
        *(uint4*)(dst + (row0 + r) * 64 + c0) = *(uint4*)&tmp[0];
        *(uint4*)(dst + (row0 + r) * 64 + c0 + 8) = *(uint4*)&tmp[8];
    }
}

// ---------------------------------------------------------------------------
// Spart[ks][b][j][d] = sum_{n in ks-slice} K[b,n,j] * x[b,n,d]
// grid (16 d-tiles, 8 ksplit, 8 b) = 1024 blocks (4/CU). Conflict-free LDS
// transpose (lane = n), reg prefetch of next 64-n chunk.
// ---------------------------------------------------------------------------
__global__ __launch_bounds__(256) void s_kernel(
    const u16* __restrict__ Kb, const float* __restrict__ x,
    float* __restrict__ Sp)
{
    __shared__ __align__(16) u16 Kt[64 * 72];
    __shared__ __align__(16) u16 Xt[64 * 72];

    const int tid = threadIdx.x, lane = tid & 63, wv = tid >> 6;
    const int dt = blockIdx.x, ks = blockIdx.y, b = blockIdx.z;
    const int n0 = ks * 256, d0 = dt * 64;

    const u16*   Kp = Kb + ((long)b * 2048 + n0) * 64;
    const float* xp = x  + ((long)b * 2048 + n0) * 1024 + d0;

    const f32x4 zero = {0.f, 0.f, 0.f, 0.f};
    f32x4 acc[4];
#pragma unroll
    for (int i = 0; i < 4; ++i) acc[i] = zero;

    uint4 kv0, kv1;
    float4 xv[4];
#define SK_LOAD(NB)                                                           \
    {                                                                         \
        kv0 = *(const uint4*)(Kp + (long)((NB) + lane) * 64 + wv * 16);       \
        kv1 = *(const uint4*)(Kp + (long)((NB) + lane) * 64 + wv * 16 + 8);   \
        _Pragma("unroll")                                                     \
        for (int i = 0; i < 4; ++i)                                           \
            xv[i] = *(const float4*)(xp + (long)((NB) + lane) * 1024 + wv * 16 + i * 4); \
    }

    SK_LOAD(0)
    for (int ch = 0; ch < 4; ++ch) {
        if (ch) __syncthreads();
#pragma unroll
        for (int i = 0; i < 8; ++i)
            Kt[(wv * 16 + i) * 72 + lane] = ((const u16*)&kv0)[i];
#pragma unroll
        for (int i = 0; i < 8; ++i)
            Kt[(wv * 16 + 8 + i) * 72 + lane] = ((const u16*)&kv1)[i];
#pragma unroll
        for (int i = 0; i < 4; ++i) {
            Xt[(wv * 16 + i * 4 + 0) * 72 + lane] = f2bf(xv[i].x);
            Xt[(wv * 16 + i * 4 + 1) * 72 + lane] = f2bf(xv[i].y);
            Xt[(wv * 16 + i * 4 + 2) * 72 + lane] = f2bf(xv[i].z);
            Xt[(wv * 16 + i * 4 + 3) * 72 + lane] = f2bf(xv[i].w);
        }
        __syncthreads();
        if (ch < 3) SK_LOAD((ch + 1) * 64)
#pragma unroll
        for (int kk = 0; kk < 64; kk += 32) {
            bf16x8 a = frag(Kt, wv * 16, lane, kk);
#pragma unroll
            for (int ct = 0; ct < 4; ++ct)
                acc[ct] = MFMA16(a, frag(Xt, ct * 16, lane, kk), acc[ct]);
        }
    }
#undef SK_LOAD

    float* C = Sp + ((long)ks * 8 + b) * 65536 + d0;
    const int rr = wv * 16 + (lane >> 4) * 4;
    const int cc = lane & 15;
#pragma unroll
    for (int ct = 0; ct < 4; ++ct)
#pragma unroll
        for (int g = 0; g < 4; ++g)
            C[(long)(rr + g) * 1024 + ct * 16 + cc] = acc[ct][g];
}

// ---------------------------------------------------------------------------
// 64x64 MFMA NT-GEMM: C[m,n] (+)= sum_k (sum_s A_s[m,k]) * (sum_s B_s[n,k])
// AMODE/BMODE: 0 = fp32 row-major [dim][k]; 1 = bf16 row-major.
// SPLIT: hi/lo 3-product accuracy. Two-phase unrolled staging + reg prefetch.
// grid = (Mtiles, Ntiles, batch*nksplit).
// ---------------------------------------------------------------------------
template <int AMODE, int BMODE, bool SPLIT, int ASLAB, int BSLAB, bool ACCUM>
__global__ __launch_bounds__(256) void mm_nt(
    const void* __restrict__ Ap, int lda, long bsA, long slabA,
    const void* __restrict__ Bp, int ldb, long bsB, long slabB,
    float* __restrict__ Cp, int ldc, long bsC, long splitC,
    int Kred, int nksplit)
{
    __shared__ __align__(16) u16 SMEM[(SPLIT ? 4 : 2) * 4608];
    u16* Ah = SMEM;
    u16* Bh = SMEM + 4608;
    u16* Al = SPLIT ? SMEM + 2 * 4608 : nullptr;
    u16* Bl = SPLIT ? SMEM + 3 * 4608 : nullptr;

    const int tid = threadIdx.x, lane = tid & 63, wv = tid >> 6;
    const int bm = blockIdx.x, bn = blockIdx.y;
    const int batch = blockIdx.z / nksplit;
    const int ks = blockIdx.z % nksplit;
    const int Kper = Kred / nksplit;
    const long kOff = (long)ks * Kper;

    const int r4 = tid >> 4, k4 = (tid & 15) * 4;   // mode-0 staging coords
    const int r8 = tid >> 3, k8 = (tid & 7) * 8;    // mode-1 staging coords

    const f32x4 zero = {0.f, 0.f, 0.f, 0.f};
    f32x4 acc[4];
#pragma unroll
    for (int i = 0; i < 4; ++i) acc[i] = zero;

    float4 fva[4], fvb[4];
    uint4  uva[2], uvb[2];

#define MM_LOADA(K0)                                                          \
    if constexpr (AMODE == 0) {                                               \
        const float* A = (const float*)Ap + (long)batch * bsA                 \
                       + (long)bm * 64 * lda + (K0);                          \
        _Pragma("unroll")                                                     \
        for (int i = 0; i < 4; ++i) {                                         \
            const float* p = A + (long)(r4 + i * 16) * lda + k4;              \
            float4 v = *(const float4*)p;                                     \
            _Pragma("unroll")                                                 \
            for (int s = 1; s < ASLAB; ++s) {                                 \
                float4 w = *(const float4*)(p + (long)s * slabA);             \
                v.x += w.x; v.y += w.y; v.z += w.z; v.w += w.w;               \
            }                                                                 \
            fva[i] = v;                                                       \
        }                                                                     \
    } else {                                                                  \
        const u16* A = (const u16*)Ap + (long)batch * bsA                     \
                     + (long)bm * 64 * lda + (K0);                            \
        _Pragma("unroll")                                                     \
        for (int i = 0; i < 2; ++i)                                           \
            uva[i] = *(const uint4*)(A + (long)(r8 + i * 32) * lda + k8);     \
    }
#define MM_LOADB(K0)                                                          \
    if constexpr (BMODE == 0) {                                               \
        const float* Bq = (const float*)Bp + (long)batch * bsB                \
                        + (long)bn * 64 * ldb + (K0);                         \
        _Pragma("unroll")                                                     \
        for (int i = 0; i < 4; ++i) {                                         \
            const float* p = Bq + (long)(r4 + i * 16) * ldb + k4;             \
            float4 v = *(const float4*)p;                                     \
            _Pragma("unroll")                                                 \
            for (int s = 1; s < BSLAB; ++s) {                                 \
                float4 w = *(const float4*)(p + (long)s * slabB);             \
                v.x += w.x; v.y += w.y; v.z += w.z; v.w += w.w;               \
            }                                                                 \
            fvb[i] = v;                                                       \
        }                                                                     \
    } else {                                                                  \
        const u16* Bq = (const u16*)Bp + (long)batch * bsB                    \
                      + (long)bn * 64 * ldb + (K0);                           \
        _Pragma("unroll")                                                     \
        for (int i = 0; i < 2; ++i)                                           \
            uvb[i] = *(const uint4*)(Bq + (long)(r8 + i * 32) * ldb + k8);    \
    }

    MM_LOADA(kOff) MM_LOADB(kOff)
    for (int k0 = 0; k0 < Kper; k0 += 64) {
        if (k0) __syncthreads();
        // ---- store phase A ----
        if constexpr (AMODE == 0) {
#pragma unroll
            for (int i = 0; i < 4; ++i) {
                int r = r4 + i * 16;
                ushort4 h;
                h.x = f2bf(fva[i].x); h.y = f2bf(fva[i].y);
                h.z = f2bf(fva[i].z); h.w = f2bf(fva[i].w);
                *(ushort4*)&Ah[r * 72 + k4] = h;
                if constexpr (SPLIT) {
                    ushort4 l;
                    l.x = f2bf(fva[i].x - bf2f(h.x)); l.y = f2bf(fva[i].y - bf2f(h.y));
                    l.z = f2bf(fva[i].z - bf2f(h.z)); l.w = f2bf(fva[i].w - bf2f(h.w));
                    *(ushort4*)&Al[r * 72 + k4] = l;
                }
            }
        } else {
#pragma unroll
            for (int i = 0; i < 2; ++i)
                *(uint4*)&Ah[(r8 + i * 32) * 72 + k8] = uva[i];
        }
        // ---- store phase B ----
        if constexpr (BMODE == 0) {
#pragma unroll
            for (int i = 0; i < 4; ++i) {
                int r = r4 + i * 16;
                ushort4 h;
                h.x = f2bf(fvb[i].x); h.y = f2bf(fvb[i].y);
                h.z = f2bf(fvb[i].z); h.w = f2bf(fvb[i].w);
                *(ushort4*)&Bh[r * 72 + k4] = h;
                if constexpr (SPLIT) {
                    ushort4 l;
                    l.x = f2bf(fvb[i].x - bf2f(h.x)); l.y = f2bf(fvb[i].y - bf2f(h.y));
                    l.z = f2bf(fvb[i].z - bf2f(h.z)); l.w = f2bf(fvb[i].w - bf2f(h.w));
                    *(ushort4*)&Bl[r * 72 + k4] = l;
                }
            }
        } else {
#pragma unroll
            for (int i = 0; i < 2; ++i)
                *(uint4*)&Bh[(r8 + i * 32) * 72 + k8] = uvb[i];
        }
        __syncthreads();
        if (k0 + 64 < Kper) { MM_LOADA(kOff + k0 + 64) MM_LOADB(kOff + k0 + 64) }
#pragma unroll
        for (int kk = 0; kk < 64; kk += 32) {
            bf16x8 ah = frag(Ah, wv * 16, lane, kk);
            bf16x8 al;
            if constexpr (SPLIT) al = frag(Al, wv * 16, lane, kk);
#pragma unroll
            for (int ct = 0; ct < 4; ++ct) {
                bf16x8 bh = frag(Bh, ct * 16, lane, kk);
                acc[ct] = MFMA16(ah, bh, acc[ct]);
                if constexpr (SPLIT) {
                    acc[ct] = MFMA16(al, bh, acc[ct]);
                    acc[ct] = MFMA16(ah, frag(Bl, ct * 16, lane, kk), acc[ct]);
                }
            }
        }
    }
#undef MM_LOADA
#undef MM_LOADB

    float* C = Cp + (long)batch * bsC + (long)ks * splitC
             + (long)bm * 64 * ldc + (long)bn * 64;
    const int rr = wv * 16 + (lane >> 4) * 4;
    const int cc = lane & 15;
#pragma unroll
    for (int ct = 0; ct < 4; ++ct)
#pragma unroll
        for (int g = 0; g < 4; ++g) {
            long idx = (long)(rr + g) * ldc + ct * 16 + cc;
            if constexpr (ACCUM) C[idx] += acc[ct][g];
            else                 C[idx] = acc[ct][g];
        }
}

// ---------------------------------------------------------------------------
extern "C" void kernel_launch(void* const* d_in, const int* in_sizes, int n_in,
                              void* d_out, int out_size, void* d_ws, size_t ws_size,
                              hipStream_t stream)
{
    const float* x  = (const float*)d_in[0];
    const float* Wq = (const float*)d_in[1];
    const float* Wk = (const float*)d_in[2];
    const float* Wv = (const float*)d_in[3];
    const float* W1 = (const float*)d_in[4];
    const float* W2 = (const float*)d_in[5];
    float* out = (float*)d_out;

    // Scratch (bytes): Qb 2M, Kb 2M, fcb 4M, Sp(8 slabs) 16M, Mp(4 slabs) 8M, PBp 2M
    const size_t QB = 2097152, KBY = 2097152, FCB = 4194304,
                 SPB = 16777216, MBY = 8388608, PBB = 2097152;
    const size_t need = QB + KBY + FCB + SPB + MBY + PBB;  // 34 MB

    u16 *Qb, *Kb;
    float *fcb, *Sp, *Mp, *PBp;
    if (ws_size >= need) {
        char* w = (char*)d_ws;
        Qb  = (u16*)w;    w += QB;
        Kb  = (u16*)w;    w += KBY;
        fcb = (float*)w;  w += FCB;
        Sp  = (float*)w;  w += SPB;
        Mp  = (float*)w;  w += MBY;
        PBp = (float*)w;
    } else {
        // Scratch in d_out (all dead before the final GEMM overwrites it);
        // fcb (read concurrently with out writes) in ws.
        char* o = (char*)d_out;
        Qb  = (u16*)o;    o += QB;
        Kb  = (u16*)o;    o += KBY;
        Sp  = (float*)o;  o += SPB;
        Mp  = (float*)o;  o += MBY;
        PBp = (float*)o;
        fcb = (float*)d_ws;
    }

    // 1) Q,K (bf16) + fc = x*W1^T (split-accurate fp32)
    qkf_kernel<<<dim3(256), 256, 0, stream>>>(x, Wq, Wk, W1, Qb, Kb, fcb);

    // 2) Spart[ks8][b][j][d] = K_slice^T * x_slice  (1024 blocks)
    s_kernel<<<dim3(16, 8, 8), 256, 0, stream>>>(Kb, x, Sp);

    // 3) Mpart[ks4][b][j][e] = (sum_8 Spart)[j,:] * Wv^T  (512 blocks, d-split 4)
    mm_nt<0, 0, false, 8, 1, false><<<dim3(1, 16, 32), 256, 0, stream>>>(
        Sp, 1024, 65536L, 524288L,   Wv, 1024, 0, 0,
        Mp, 1024, 65536L, 524288L, 1024, 4);

    // 4) PBTpart[ks16][b][k][j] = W1[k,:] * (sum_4 Mpart)[j,:]^T  (128 blocks, e-split 16)
    mm_nt<0, 0, false, 1, 4, false><<<dim3(1, 1, 128), 256, 0, stream>>>(
        W1, 1024, 0, 0,   Mp, 1024, 65536L, 524288L,
        PBp, 64, 4096L, 32768L, 1024, 16);

    // 5) fc[b,n,k] += Q[b,n,:] * (sum_16 PBTpart)[k,:]^T  (256 blocks)
    mm_nt<1, 0, false, 1, 16, true><<<dim3(32, 1, 8), 256, 0, stream>>>(
        Qb, 64, 131072L, 0,   PBp, 64, 4096L, 32768L,
        fcb, 64, 131072L, 0, 64, 1);

    // 6) out = fc * W2^T (split-accurate both operands, 4096 blocks)
    mm_nt<0, 0, true, 1, 1, false><<<dim3(256, 16, 1), 256, 0, stream>>>(
        fcb, 64, 0, 0,   W2, 64, 0, 0,
        out, 1024, 0, 0, 64, 1);
}

// Round 4
// 207.004 us; speedup vs baseline: 2.4592x; 1.0646x over previous
//
#include <hip/hip_runtime.h>

typedef __attribute__((ext_vector_type(8))) __bf16 bf16x8;
typedef __attribute__((ext_vector_type(4))) float f32x4;
typedef unsigned short u16;

#define MFMA16(a, b, c) __builtin_amdgcn_mfma_f32_16x16x32_bf16(a, b, c, 0, 0, 0)

__device__ __forceinline__ u16 f2bf(float f) {
    unsigned u = __float_as_uint(f);
    unsigned r = ((u >> 16) & 1u) + 0x7fffu;  // RNE
    return (u16)((u + r) >> 16);
}
__device__ __forceinline__ float bf2f(u16 h) {
    return __uint_as_float(((unsigned)h) << 16);
}
// LDS fragment: row = rtile + (lane&15), k = kofs + (lane>>4)*8; row stride 72 u16 (144B)
__device__ __forceinline__ bf16x8 frag(const u16* base, int rtile, int lane, int kofs) {
    return *(const bf16x8*)(base + (rtile + (lane & 15)) * 72 + kofs + (lane >> 4) * 8);
}

// ---------------------------------------------------------------------------
// Fused partial: for k-half ks (blockIdx.y), 64 rows (blockIdx.x):
//   Qp[ks] = x*Wq^T, Kp[ks] = x*Wk^T (fp32 partials)
//   fcp[ks] = x*W1^T (fp32, 3-product bf16 split)
// 512 blocks -> 2 blocks/CU, 8 waves/CU.
// ---------------------------------------------------------------------------
__global__ __launch_bounds__(256) void qkf_kernel(
    const float* __restrict__ x, const float* __restrict__ Wq,
    const float* __restrict__ Wk, const float* __restrict__ W1,
    float* __restrict__ Qp, float* __restrict__ Kp, float* __restrict__ fcp)
{
    __shared__ __align__(16) u16 SM[6 * 4608];
    u16* Xh  = SM;
    u16* Xl  = SM + 4608;
    u16* Wqh = SM + 2 * 4608;
    u16* Wkh = SM + 3 * 4608;
    u16* W1h = SM + 4 * 4608;
    u16* W1l = SM + 5 * 4608;

    const int tid  = threadIdx.x;
    const int lane = tid & 63;
    const int wv   = tid >> 6;
    const int r0   = wv * 16;
    const long row0 = (long)blockIdx.x * 64;
    const int kb   = blockIdx.y * 512;          // k-half base
    const long sOf = (long)blockIdx.y * 1048576; // output slab offset

    const f32x4 zero = {0.f, 0.f, 0.f, 0.f};
    f32x4 qa[4], ka[4], fa[4];
#pragma unroll
    for (int i = 0; i < 4; ++i) { qa[i] = zero; ka[i] = zero; fa[i] = zero; }

    const int sr = tid >> 4;         // staging row 0..15
    const int sk = (tid & 15) * 4;   // staging k   0..60

    float4 xv[4], qv[4], kv[4], w1v[4];
#define QKF_LOAD(K0)                                                          \
    {                                                                         \
        _Pragma("unroll")                                                     \
        for (int i = 0; i < 4; ++i) {                                         \
            int r = sr + i * 16;                                              \
            xv[i]  = *(const float4*)(x  + (row0 + r) * 1024 + (K0) + sk);    \
            qv[i]  = *(const float4*)(Wq + (long)r * 1024 + (K0) + sk);       \
            kv[i]  = *(const float4*)(Wk + (long)r * 1024 + (K0) + sk);       \
            w1v[i] = *(const float4*)(W1 + (long)r * 1024 + (K0) + sk);       \
        }                                                                     \
    }

    QKF_LOAD(kb)
    for (int ch = 0; ch < 8; ++ch) {
        if (ch) __syncthreads();
#pragma unroll
        for (int i = 0; i < 4; ++i) {
            int r = sr + i * 16;
            ushort4 h, l;
            h.x = f2bf(xv[i].x); l.x = f2bf(xv[i].x - bf2f(h.x));
            h.y = f2bf(xv[i].y); l.y = f2bf(xv[i].y - bf2f(h.y));
            h.z = f2bf(xv[i].z); l.z = f2bf(xv[i].z - bf2f(h.z));
            h.w = f2bf(xv[i].w); l.w = f2bf(xv[i].w - bf2f(h.w));
            *(ushort4*)&Xh[r * 72 + sk] = h;
            *(ushort4*)&Xl[r * 72 + sk] = l;
            ushort4 hq;
            hq.x = f2bf(qv[i].x); hq.y = f2bf(qv[i].y);
            hq.z = f2bf(qv[i].z); hq.w = f2bf(qv[i].w);
            *(ushort4*)&Wqh[r * 72 + sk] = hq;
            ushort4 hk;
            hk.x = f2bf(kv[i].x); hk.y = f2bf(kv[i].y);
            hk.z = f2bf(kv[i].z); hk.w = f2bf(kv[i].w);
            *(ushort4*)&Wkh[r * 72 + sk] = hk;
            ushort4 hw, lw;
            hw.x = f2bf(w1v[i].x); lw.x = f2bf(w1v[i].x - bf2f(hw.x));
            hw.y = f2bf(w1v[i].y); lw.y = f2bf(w1v[i].y - bf2f(hw.y));
            hw.z = f2bf(w1v[i].z); lw.z = f2bf(w1v[i].z - bf2f(hw.z));
            hw.w = f2bf(w1v[i].w); lw.w = f2bf(w1v[i].w - bf2f(hw.w));
            *(ushort4*)&W1h[r * 72 + sk] = hw;
            *(ushort4*)&W1l[r * 72 + sk] = lw;
        }
        __syncthreads();
        if (ch < 7) QKF_LOAD(kb + (ch + 1) * 64)
#pragma unroll
        for (int kk = 0; kk < 64; kk += 32) {
            bf16x8 ah = frag(Xh, r0, lane, kk);
            bf16x8 al = frag(Xl, r0, lane, kk);
#pragma unroll
            for (int ct = 0; ct < 4; ++ct) {
                qa[ct] = MFMA16(ah, frag(Wqh, ct * 16, lane, kk), qa[ct]);
                ka[ct] = MFMA16(ah, frag(Wkh, ct * 16, lane, kk), ka[ct]);
                bf16x8 bh = frag(W1h, ct * 16, lane, kk);
                fa[ct] = MFMA16(ah, bh, fa[ct]);
                fa[ct] = MFMA16(al, bh, fa[ct]);
                fa[ct] = MFMA16(ah, frag(W1l, ct * 16, lane, kk), fa[ct]);
            }
        }
    }
#undef QKF_LOAD

    // fp32 partial stores (C layout: col=lane&15, row=quad*4+g)
    const int rr = r0 + (lane >> 4) * 4;
    const int cc = lane & 15;
#pragma unroll
    for (int ct = 0; ct < 4; ++ct)
#pragma unroll
        for (int g = 0; g < 4; ++g) {
            long o = sOf + (row0 + rr + g) * 64 + ct * 16 + cc;
            Qp[o]  = qa[ct][g];
            Kp[o]  = ka[ct][g];
            fcp[o] = fa[ct][g];
        }
}

// ---------------------------------------------------------------------------
// Sp[ks][b][j][d] = sum_{n in ks-slice} K[b,n,j] * x[b,n,d]
// K comes as 2 fp32 slabs (summed at staging). grid (16,8,8) = 1024 blocks.
// ---------------------------------------------------------------------------
__global__ __launch_bounds__(256) void s_kernel(
    const float* __restrict__ Kp, const float* __restrict__ x,
    float* __restrict__ Sp)
{
    __shared__ __align__(16) u16 Kt[64 * 72];
    __shared__ __align__(16) u16 Xt[64 * 72];

    const int tid = threadIdx.x, lane = tid & 63, wv = tid >> 6;
    const int dt = blockIdx.x, ks = blockIdx.y, b = blockIdx.z;
    const int n0 = ks * 256, d0 = dt * 64;

    const float* Kq = Kp + ((long)b * 2048 + n0) * 64;
    const float* xp = x  + ((long)b * 2048 + n0) * 1024 + d0;

    const f32x4 zero = {0.f, 0.f, 0.f, 0.f};
    f32x4 acc[4];
#pragma unroll
    for (int i = 0; i < 4; ++i) acc[i] = zero;

    float4 kf[4], xv[4];
#define SK_LOAD(NB)                                                           \
    {                                                                         \
        _Pragma("unroll")                                                     \
        for (int i = 0; i < 4; ++i) {                                         \
            float4 a = *(const float4*)(Kq + (long)((NB) + lane) * 64 + wv * 16 + i * 4); \
            float4 c = *(const float4*)(Kq + 1048576 + (long)((NB) + lane) * 64 + wv * 16 + i * 4); \
            kf[i].x = a.x + c.x; kf[i].y = a.y + c.y;                         \
            kf[i].z = a.z + c.z; kf[i].w = a.w + c.w;                         \
            xv[i] = *(const float4*)(xp + (long)((NB) + lane) * 1024 + wv * 16 + i * 4); \
        }                                                                     \
    }

    SK_LOAD(0)
    for (int ch = 0; ch < 4; ++ch) {
        if (ch) __syncthreads();
#pragma unroll
        for (int i = 0; i < 4; ++i) {
            Kt[(wv * 16 + i * 4 + 0) * 72 + lane] = f2bf(kf[i].x);
            Kt[(wv * 16 + i * 4 + 1) * 72 + lane] = f2bf(kf[i].y);
            Kt[(wv * 16 + i * 4 + 2) * 72 + lane] = f2bf(kf[i].z);
            Kt[(wv * 16 + i * 4 + 3) * 72 + lane] = f2bf(kf[i].w);
            Xt[(wv * 16 + i * 4 + 0) * 72 + lane] = f2bf(xv[i].x);
            Xt[(wv * 16 + i * 4 + 1) * 72 + lane] = f2bf(xv[i].y);
            Xt[(wv * 16 + i * 4 + 2) * 72 + lane] = f2bf(xv[i].z);
            Xt[(wv * 16 + i * 4 + 3) * 72 + lane] = f2bf(xv[i].w);
        }
        __syncthreads();
        if (ch < 3) SK_LOAD((ch + 1) * 64)
#pragma unroll
        for (int kk = 0; kk < 64; kk += 32) {
            bf16x8 a = frag(Kt, wv * 16, lane, kk);
#pragma unroll
            for (int ct = 0; ct < 4; ++ct)
                acc[ct] = MFMA16(a, frag(Xt, ct * 16, lane, kk), acc[ct]);
        }
    }
#undef SK_LOAD

    float* C = Sp + ((long)ks * 8 + b) * 65536 + d0;
    const int rr = wv * 16 + (lane >> 4) * 4;
    const int cc = lane & 15;
#pragma unroll
    for (int ct = 0; ct < 4; ++ct)
#pragma unroll
        for (int g = 0; g < 4; ++g)
            C[(long)(rr + g) * 1024 + ct * 16 + cc] = acc[ct][g];
}

// ---------------------------------------------------------------------------
// 64x64 MFMA NT-GEMM: C[m,n] = sum_s Cin_s[m,n] + sum_k (sum A_s)*(sum B_s)
// AMODE: 0 fp32 row-major, 1 bf16 row-major.
// BMODE: 0 fp32 row-major, 1 bf16 row-major, 2 fp32 transposed [k][n].
// SPLIT: hi/lo 3-product accuracy. CSLAB: #fp32 C-init slabs (0 = none).
// ---------------------------------------------------------------------------
template <int AMODE, int BMODE, bool SPLIT, int ASLAB, int BSLAB, int CSLAB>
__global__ __launch_bounds__(256) void mm_nt(
    const void* __restrict__ Ap, int lda, long bsA, long slabA,
    const void* __restrict__ Bp, int ldb, long bsB, long slabB,
    float* __restrict__ Cp, int ldc, long bsC, long splitC,
    const float* __restrict__ Cin, long slabCin,
    int Kred, int nksplit)
{
    __shared__ __align__(16) u16 SMEM[(SPLIT ? 4 : 2) * 4608];
    u16* Ah = SMEM;
    u16* Bh = SMEM + 4608;
    u16* Al = SPLIT ? SMEM + 2 * 4608 : nullptr;
    u16* Bl = SPLIT ? SMEM + 3 * 4608 : nullptr;

    const int tid = threadIdx.x, lane = tid & 63, wv = tid >> 6;
    const int bm = blockIdx.x, bn = blockIdx.y;
    const int batch = blockIdx.z / nksplit;
    const int ks = blockIdx.z % nksplit;
    const int Kper = Kred / nksplit;
    const long kOff = (long)ks * Kper;

    const int r4 = tid >> 4, k4 = (tid & 15) * 4;   // mode-0 staging coords
    const int r8 = tid >> 3, k8 = (tid & 7) * 8;    // mode-1 staging coords

    const f32x4 zero = {0.f, 0.f, 0.f, 0.f};
    f32x4 acc[4];
#pragma unroll
    for (int i = 0; i < 4; ++i) acc[i] = zero;

    float4 fva[4], fvb[4];
    uint4  uva[2], uvb[2];
    float  tvb[16];

#define MM_LOADA(K0)                                                          \
    if constexpr (AMODE == 0) {                                               \
        const float* A = (const float*)Ap + (long)batch * bsA                 \
                       + (long)bm * 64 * lda + (K0);                          \
        _Pragma("unroll")                                                     \
        for (int i = 0; i < 4; ++i) {                                         \
            const float* p = A + (long)(r4 + i * 16) * lda + k4;              \
            float4 v = *(const float4*)p;                                     \
            _Pragma("unroll")                                                 \
            for (int s = 1; s < ASLAB; ++s) {                                 \
                float4 w = *(const float4*)(p + (long)s * slabA);             \
                v.x += w.x; v.y += w.y; v.z += w.z; v.w += w.w;               \
            }                                                                 \
            fva[i] = v;                                                       \
        }                                                                     \
    } else {                                                                  \
        const u16* A = (const u16*)Ap + (long)batch * bsA                     \
                     + (long)bm * 64 * lda + (K0);                            \
        _Pragma("unroll")                                                     \
        for (int i = 0; i < 2; ++i)                                           \
            uva[i] = *(const uint4*)(A + (long)(r8 + i * 32) * lda + k8);     \
    }
#define MM_LOADB(K0)                                                          \
    if constexpr (BMODE == 0) {                                               \
        const float* Bq = (const float*)Bp + (long)batch * bsB                \
                        + (long)bn * 64 * ldb + (K0);                         \
        _Pragma("unroll")                                                     \
        for (int i = 0; i < 4; ++i) {                                         \
            const float* p = Bq + (long)(r4 + i * 16) * ldb + k4;             \
            float4 v = *(const float4*)p;                                     \
            _Pragma("unroll")                                                 \
            for (int s = 1; s < BSLAB; ++s) {                                 \
                float4 w = *(const float4*)(p + (long)s * slabB);             \
                v.x += w.x; v.y += w.y; v.z += w.z; v.w += w.w;               \
            }                                                                 \
            fvb[i] = v;                                                       \
        }                                                                     \
    } else if constexpr (BMODE == 1) {                                        \
        const u16* Bq = (const u16*)Bp + (long)batch * bsB                    \
                      + (long)bn * 64 * ldb + (K0);                           \
        _Pragma("unroll")                                                     \
        for (int i = 0; i < 2; ++i)                                           \
            uvb[i] = *(const uint4*)(Bq + (long)(r8 + i * 32) * ldb + k8);    \
    } else {                                                                  \
        const float* Bq = (const float*)Bp + (long)batch * bsB                \
                        + (long)(K0) * ldb + (long)bn * 64;                   \
        _Pragma("unroll")                                                     \
        for (int i = 0; i < 16; ++i)                                          \
            tvb[i] = Bq[(long)((tid >> 6) + i * 4) * ldb + (tid & 63)];       \
    }

    MM_LOADA(kOff) MM_LOADB(kOff)
    for (int k0 = 0; k0 < Kper; k0 += 64) {
        if (k0) __syncthreads();
        // ---- store phase A ----
        if constexpr (AMODE == 0) {
#pragma unroll
            for (int i = 0; i < 4; ++i) {
                int r = r4 + i * 16;
                ushort4 h;
                h.x = f2bf(fva[i].x); h.y = f2bf(fva[i].y);
                h.z = f2bf(fva[i].z); h.w = f2bf(fva[i].w);
                *(ushort4*)&Ah[r * 72 + k4] = h;
                if constexpr (SPLIT) {
                    ushort4 l;
                    l.x = f2bf(fva[i].x - bf2f(h.x)); l.y = f2bf(fva[i].y - bf2f(h.y));
                    l.z = f2bf(fva[i].z - bf2f(h.z)); l.w = f2bf(fva[i].w - bf2f(h.w));
                    *(ushort4*)&Al[r * 72 + k4] = l;
                }
            }
        } else {
#pragma unroll
            for (int i = 0; i < 2; ++i)
                *(uint4*)&Ah[(r8 + i * 32) * 72 + k8] = uva[i];
        }
        // ---- store phase B ----
        if constexpr (BMODE == 0) {
#pragma unroll
            for (int i = 0; i < 4; ++i) {
                int r = r4 + i * 16;
                ushort4 h;
                h.x = f2bf(fvb[i].x); h.y = f2bf(fvb[i].y);
                h.z = f2bf(fvb[i].z); h.w = f2bf(fvb[i].w);
                *(ushort4*)&Bh[r * 72 + k4] = h;
                if constexpr (SPLIT) {
                    ushort4 l;
                    l.x = f2bf(fvb[i].x - bf2f(h.x)); l.y = f2bf(fvb[i].y - bf2f(h.y));
                    l.z = f2bf(fvb[i].z - bf2f(h.z)); l.w = f2bf(fvb[i].w - bf2f(h.w));
                    *(ushort4*)&Bl[r * 72 + k4] = l;
                }
            }
        } else if constexpr (BMODE == 1) {
#pragma unroll
            for (int i = 0; i < 2; ++i)
                *(uint4*)&Bh[(r8 + i * 32) * 72 + k8] = uvb[i];
        } else {
#pragma unroll
            for (int i = 0; i < 16; ++i)
                Bh[(tid & 63) * 72 + (tid >> 6) + i * 4] = f2bf(tvb[i]);
        }
        __syncthreads();
        if (k0 + 64 < Kper) { MM_LOADA(kOff + k0 + 64) MM_LOADB(kOff + k0 + 64) }
#pragma unroll
        for (int kk = 0; kk < 64; kk += 32) {
            bf16x8 ah = frag(Ah, wv * 16, lane, kk);
            bf16x8 al;
            if constexpr (SPLIT) al = frag(Al, wv * 16, lane, kk);
#pragma unroll
            for (int ct = 0; ct < 4; ++ct) {
                bf16x8 bh = frag(Bh, ct * 16, lane, kk);
                acc[ct] = MFMA16(ah, bh, acc[ct]);
                if constexpr (SPLIT) {
                    acc[ct] = MFMA16(al, bh, acc[ct]);
                    acc[ct] = MFMA16(ah, frag(Bl, ct * 16, lane, kk), acc[ct]);
                }
            }
        }
    }
#undef MM_LOADA
#undef MM_LOADB

    const long coff = (long)batch * bsC + (long)bm * 64 * ldc + (long)bn * 64;
    float* C = Cp + coff + (long)ks * splitC;
    const int rr = wv * 16 + (lane >> 4) * 4;
    const int cc = lane & 15;
#pragma unroll
    for (int ct = 0; ct < 4; ++ct)
#pragma unroll
        for (int g = 0; g < 4; ++g) {
            long idx = (long)(rr + g) * ldc + ct * 16 + cc;
            float v = acc[ct][g];
            if constexpr (CSLAB > 0) {
                const float* Ci = Cin + coff + idx;
#pragma unroll
                for (int s = 0; s < CSLAB; ++s) v += Ci[(long)s * slabCin];
            }
            C[idx] = v;
        }
}

// ---------------------------------------------------------------------------
extern "C" void kernel_launch(void* const* d_in, const int* in_sizes, int n_in,
                              void* d_out, int out_size, void* d_ws, size_t ws_size,
                              hipStream_t stream)
{
    const float* x  = (const float*)d_in[0];
    const float* Wq = (const float*)d_in[1];
    const float* Wk = (const float*)d_in[2];
    const float* Wv = (const float*)d_in[3];
    const float* W1 = (const float*)d_in[4];
    const float* W2 = (const float*)d_in[5];
    float* out = (float*)d_out;

    // Scratch (bytes): Qp 8M (2 slabs), Kp 8M, fcp 8M, Sp 16M, Gp 2M, PBp 2M, fcb 4M
    const size_t QPB = 8388608, KPB = 8388608, FCPB = 8388608,
                 SPB = 16777216, GPB = 2097152, PBB = 2097152, FCB = 4194304;
    const size_t need = QPB + KPB + FCPB + SPB + GPB + PBB + FCB;  // 50 MB

    float *Qp, *Kp, *fcp, *Sp, *Gp, *PBp, *fcb;
    if (ws_size >= need) {
        char* w = (char*)d_ws;
        Qp  = (float*)w;  w += QPB;
        Kp  = (float*)w;  w += KPB;
        fcp = (float*)w;  w += FCPB;
        Sp  = (float*)w;  w += SPB;
        Gp  = (float*)w;  w += GPB;
        PBp = (float*)w;  w += PBB;
        fcb = (float*)w;
    } else {
        // Scratch in d_out (all dead before the final GEMM overwrites it);
        // fcb (read concurrently with out writes) in ws.
        char* o = (char*)d_out;
        Qp  = (float*)o;  o += QPB;
        Kp  = (float*)o;  o += KPB;
        fcp = (float*)o;  o += FCPB;
        Sp  = (float*)o;  o += SPB;
        Gp  = (float*)o;  o += GPB;
        PBp = (float*)o;
        fcb = (float*)d_ws;
    }

    // 1) Qp/Kp/fcp partials over k-halves (512 blocks, 2/CU)
    qkf_kernel<<<dim3(256, 2), 256, 0, stream>>>(x, Wq, Wk, W1, Qp, Kp, fcp);

    // 2) Sp[ks8][b][j][d] = (Kp0+Kp1)_slice^T * x_slice  (1024 blocks)
    s_kernel<<<dim3(16, 8, 8), 256, 0, stream>>>(Kp, x, Sp);

    // 3) Gpart[ks8][k][d] = W1[k,:] * Wv[:,d]  (batch-independent, 128 blocks)
    mm_nt<0, 2, false, 1, 1, 0><<<dim3(1, 16, 8), 256, 0, stream>>>(
        W1, 1024, 0, 0,   Wv, 1024, 0, 0,
        Gp, 1024, 0, 65536L, nullptr, 0, 1024, 8);

    // 4) PBTpart[ks16][b][k][j] = (sum_8 Gpart)[k,:] * (sum_8 Sp)[b][j,:]^T  (128 blocks)
    mm_nt<0, 0, false, 8, 8, 0><<<dim3(1, 1, 128), 256, 0, stream>>>(
        Gp, 1024, 0, 65536L,   Sp, 1024, 65536L, 524288L,
        PBp, 64, 4096L, 32768L, nullptr, 0, 1024, 16);

    // 5) fcb = fcp0 + fcp1 + (Qp0+Qp1) * (sum_16 PBTpart)^T  (256 blocks)
    mm_nt<0, 0, false, 2, 16, 2><<<dim3(32, 1, 8), 256, 0, stream>>>(
        Qp, 64, 131072L, 1048576L,   PBp, 64, 4096L, 32768L,
        fcb, 64, 131072L, 0, fcp, 1048576L, 64, 1);

    // 6) out = fcb * W2^T (split-accurate both operands, 4096 blocks)
    mm_nt<0, 0, true, 1, 1, 0><<<dim3(256, 16, 1), 256, 0, stream>>>(
        fcb, 64, 0, 0,   W2, 64, 0, 0,
        out, 1024, 0, 0, nullptr, 0, 64, 1);
}